// Round 2
// baseline (381.611 us; speedup 1.0000x reference)
//
#include <hip/hip_runtime.h>
#include <hip/hip_bf16.h>

typedef unsigned int   uint;
typedef unsigned short ushort;
typedef short bf16x8 __attribute__((ext_vector_type(8)));
typedef float f32x4  __attribute__((ext_vector_type(4)));

// Problem constants
constexpr int Bm   = 512;   // molecules
constexpr int Aa   = 128;   // atoms / molecule
constexpr int Ee   = 256;   // directed bonds / molecule
constexpr int Kk   = 6;     // incoming gathered
constexpr int AFD  = 133;
constexpr int FD   = 147;   // 133+14
constexpr int Hh   = 128;
constexpr int CATD = 261;   // 133+128
constexpr int KWI  = 192;   // Wi_b row stride (147 real + 45 zero)
constexpr int KWO  = 320;   // Wo_b row stride: [0,133) atomf cols, [133,192) zero, [192,320) m2a cols
constexpr int MST  = 136;   // msg LDS row stride (bf16): 272B/row = 68 dw -> 4-bank row step, 8 groups

// ---- bf16 helpers ----------------------------------------------------------
__device__ __forceinline__ ushort f2b(float f) {
    uint u = __float_as_uint(f);
    u += 0x7FFFu + ((u >> 16) & 1u);
    return (ushort)(u >> 16);
}
__device__ __forceinline__ uint cvt2(float x, float y) {   // v_cvt_pk_bf16_f32
    float2 t2; t2.x = x; t2.y = y;
    __hip_bfloat162 t = __float22bfloat162_rn(t2);
    uint r; __builtin_memcpy(&r, &t, 4); return r;
}
__device__ __forceinline__ float2 b2f2(uint p) {
    float2 r;
    r.x = __uint_as_float(p << 16);
    r.y = __uint_as_float(p & 0xFFFF0000u);
    return r;
}

// sum 6 bf16 rows (16B slices) from LDS msg, repack to an MFMA A-frag
__device__ __forceinline__ bf16x8 gsum6(const ushort* src, const int* mr, int ko) {
    float2 s0 = {0.f, 0.f}, s1 = {0.f, 0.f}, s2 = {0.f, 0.f}, s3 = {0.f, 0.f};
#pragma unroll
    for (int k = 0; k < Kk; ++k) {
        uint4 m = *(const uint4*)&src[mr[k] + ko];
        float2 a = b2f2(m.x); s0.x += a.x; s0.y += a.y;
        float2 b = b2f2(m.y); s1.x += b.x; s1.y += b.y;
        float2 d = b2f2(m.z); s2.x += d.x; s2.y += d.y;
        float2 e = b2f2(m.w); s3.x += e.x; s3.y += e.y;
    }
    uint4 o;
    o.x = cvt2(s0.x, s0.y); o.y = cvt2(s1.x, s1.y);
    o.z = cvt2(s2.x, s2.y); o.w = cvt2(s3.x, s3.y);
    bf16x8 r;
    __builtin_memcpy(&r, &o, 16);
    return r;
}

// build A-frag straight from global fp32 (8 predicated dword loads + 4 cvt_pk)
__device__ __forceinline__ bf16x8 ld_frag_f32(const float* sp, int c0, int lim) {
    float v[8];
#pragma unroll
    for (int d = 0; d < 8; ++d) v[d] = (c0 + d < lim) ? sp[d] : 0.f;
    uint4 o;
    o.x = cvt2(v[0], v[1]); o.y = cvt2(v[2], v[3]);
    o.z = cvt2(v[4], v[5]); o.w = cvt2(v[6], v[7]);
    bf16x8 r;
    __builtin_memcpy(&r, &o, 16);
    return r;
}

// ---------------------------------------------------------------------------
// Weight prep: fp32 -> padded bf16 (tiny; runs once)
// ---------------------------------------------------------------------------
__global__ __launch_bounds__(256) void k_prep_w(const float* __restrict__ Wi,
                                                const float* __restrict__ Wh,
                                                const float* __restrict__ Wo,
                                                ushort* __restrict__ Wi_b,
                                                ushort* __restrict__ Wh_b,
                                                ushort* __restrict__ Wo_b) {
    const int h = blockIdx.x, t = threadIdx.x;
    for (int c = t; c < KWI; c += 256)
        Wi_b[h * KWI + c] = f2b(c < FD ? Wi[h * FD + c] : 0.f);
    for (int c = t; c < Hh; c += 256)
        Wh_b[h * Hh + c] = f2b(Wh[h * Hh + c]);
    for (int c = t; c < KWO; c += 256) {
        float v = 0.f;
        if (c < AFD)       v = Wo[h * CATD + c];
        else if (c >= 192) v = Wo[h * CATD + AFD + (c - 192)];
        Wo_b[h * KWO + c] = f2b(v);
    }
}

__global__ __launch_bounds__(512) void k_scan(const int* __restrict__ ml,
                                              int* __restrict__ pfx) {
    __shared__ int s[512];
    int t = threadIdx.x;
    s[t] = ml[t];
    __syncthreads();
    for (int off = 1; off < 512; off <<= 1) {
        int v = (t >= off) ? s[t - off] : 0;
        __syncthreads();
        s[t] += v;
        __syncthreads();
    }
    pfx[t + 1] = s[t];
    if (t == 0) pfx[0] = 0;
}

// ---------------------------------------------------------------------------
// Fused DMPNN, single-LDS-buffer variant. One block = one molecule.
// LDS = msg(69.6K) + maps(9.2K) = 78,848 B  ->  2 blocks/CU, 4 waves/SIMD.
//   Phase 1: inp = fini @ Wi^T   (A-frags read DIRECT from global fp32, no
//            staging, no barriers). inp kept packed-bf16 in 32 VGPRs/lane.
//            msg = relu(inp).
//   Phase 2: 2 hops, IN PLACE: acc init = inp; gather6(msg)@Wh^T accumulated
//            into acc (reads only) -> barrier -> overwrite msg=relu(acc) ->
//            barrier. New state rides in accumulators between the barriers.
//   Phase 3: readout: m2a gather part (LDS) + atomf part (direct global fp32,
//            barrier-free), masked packed store.
// 8 waves; wave owns 32 bond rows (ph1/2) / 16 atom rows (ph3).
// ---------------------------------------------------------------------------
__global__ __launch_bounds__(512, 4) void k_fused(
        const float* __restrict__ atomf,
        const float* __restrict__ fini,
        const int*   __restrict__ a2ib,
        const int*   __restrict__ mapping,
        const ushort* __restrict__ Wi_b,
        const ushort* __restrict__ Wh_b,
        const ushort* __restrict__ Wo_b,
        const float* __restrict__ bo,
        const int*   __restrict__ mol_lens,
        const int*   __restrict__ pfx,
        float* __restrict__ out,
        float* __restrict__ cmask) {
    __shared__ ushort msg[Ee * MST];       // 69,632 B
    __shared__ int    map_s[Ee * Kk];      //  6,144 B
    __shared__ int    a2_s[Aa * Kk];       //  3,072 B   -> 78,848 B total

    const int b    = blockIdx.x;
    const int tid  = threadIdx.x;
    const int wave = tid >> 6;
    const int lane = tid & 63;
    const int l15  = lane & 15, quad = lane >> 4;

    for (int i = tid; i < Ee * Kk; i += 512) map_s[i] = mapping[b * Ee * Kk + i];
    for (int i = tid; i < Aa * Kk; i += 512) a2_s[i]  = a2ib[b * Aa * Kk + i];
    const int len = mol_lens[b];
    if (tid < Aa) cmask[b * Aa + tid] = (tid < len) ? 1.0f : 0.0f;

    // ---- Phase 1: inp = fini @ Wi^T  (barrier-free) ---------------------
    f32x4 acc[2][8];
#pragma unroll
    for (int i = 0; i < 2; ++i)
#pragma unroll
        for (int j = 0; j < 8; ++j) acc[i][j] = (f32x4){0.f, 0.f, 0.f, 0.f};

    const float* fsrc = fini + (size_t)b * Ee * FD;
#pragma unroll
    for (int c = 0; c < 3; ++c) {
#pragma unroll
        for (int ks = 0; ks < 2; ++ks) {
            const int c0 = c * 64 + ks * 32 + quad * 8;   // global K col base
            bf16x8 af[2], bf[8];
#pragma unroll
            for (int i = 0; i < 2; ++i) {
                const int row = wave * 32 + i * 16 + l15;
                af[i] = ld_frag_f32(fsrc + (size_t)row * FD + c0, c0, FD);
            }
#pragma unroll
            for (int j = 0; j < 8; ++j)
                bf[j] = *(const bf16x8*)&Wi_b[(j * 16 + l15) * KWI + c0];
#pragma unroll
            for (int i = 0; i < 2; ++i)
#pragma unroll
                for (int j = 0; j < 8; ++j)
                    acc[i][j] = __builtin_amdgcn_mfma_f32_16x16x32_bf16(
                        af[i], bf[j], acc[i][j], 0, 0, 0);
        }
    }

    // inp -> packed bf16 regs; msg = relu(inp)
    uint2 inp_pk[2][8];
#pragma unroll
    for (int i = 0; i < 2; ++i)
#pragma unroll
        for (int j = 0; j < 8; ++j) {
            f32x4 a4 = acc[i][j];
            uint2 p;
            p.x = cvt2(a4[0], a4[1]);
            p.y = cvt2(a4[2], a4[3]);
            inp_pk[i][j] = p;
            int col = j * 16 + l15;
#pragma unroll
            for (int reg = 0; reg < 4; ++reg) {
                int row = wave * 32 + i * 16 + quad * 4 + reg;
                float v = a4[reg] > 0.f ? a4[reg] : 0.f;
                msg[row * MST + col] = f2b(v);
            }
        }
    __syncthreads();   // msg + map_s/a2_s visible

    // gather row offsets (same for both hops)
    int mr[2][Kk];
#pragma unroll
    for (int i = 0; i < 2; ++i) {
        int row = wave * 32 + i * 16 + l15;
#pragma unroll
        for (int k = 0; k < Kk; ++k) mr[i][k] = map_s[row * Kk + k] * MST;
    }

    // ---- Phase 2: two in-place hops -------------------------------------
#pragma unroll
    for (int h = 0; h < 2; ++h) {
        // acc starts at inp (pre-activation, bf16-rounded)
#pragma unroll
        for (int i = 0; i < 2; ++i)
#pragma unroll
            for (int j = 0; j < 8; ++j) {
                float2 lo = b2f2(inp_pk[i][j].x);
                float2 hi = b2f2(inp_pk[i][j].y);
                acc[i][j] = (f32x4){lo.x, lo.y, hi.x, hi.y};
            }
#pragma unroll
        for (int ks = 0; ks < 4; ++ks) {
            const int ko = ks * 32 + quad * 8;
            bf16x8 af[2], bf[8];
#pragma unroll
            for (int i = 0; i < 2; ++i) af[i] = gsum6(msg, mr[i], ko);
#pragma unroll
            for (int j = 0; j < 8; ++j)
                bf[j] = *(const bf16x8*)&Wh_b[(j * 16 + l15) * Hh + ko];
#pragma unroll
            for (int i = 0; i < 2; ++i)
#pragma unroll
                for (int j = 0; j < 8; ++j)
                    acc[i][j] = __builtin_amdgcn_mfma_f32_16x16x32_bf16(
                        af[i], bf[j], acc[i][j], 0, 0, 0);
        }
        __syncthreads();   // all gathers done; safe to overwrite msg
#pragma unroll
        for (int i = 0; i < 2; ++i)
#pragma unroll
            for (int j = 0; j < 8; ++j) {
                int col = j * 16 + l15;
#pragma unroll
                for (int reg = 0; reg < 4; ++reg) {
                    int row = wave * 32 + i * 16 + quad * 4 + reg;
                    float v = acc[i][j][reg];
                    msg[row * MST + col] = f2b(v > 0.f ? v : 0.f);
                }
            }
        __syncthreads();   // new msg visible
    }

    // ---- Phase 3: readout (barrier-free) --------------------------------
    f32x4 ro[8];
#pragma unroll
    for (int j = 0; j < 8; ++j) ro[j] = (f32x4){0.f, 0.f, 0.f, 0.f};

    {   // m2a gather region, K cols [192,320) of Wo
        int ar[Kk];
        const int row = wave * 16 + l15;
#pragma unroll
        for (int k = 0; k < Kk; ++k) ar[k] = a2_s[row * Kk + k] * MST;
#pragma unroll
        for (int ks = 0; ks < 4; ++ks) {
            const int ko = ks * 32 + quad * 8;
            bf16x8 a0 = gsum6(msg, ar, ko);
            bf16x8 bf[8];
#pragma unroll
            for (int j = 0; j < 8; ++j)
                bf[j] = *(const bf16x8*)&Wo_b[(j * 16 + l15) * KWO + 192 + ko];
#pragma unroll
            for (int j = 0; j < 8; ++j)
                ro[j] = __builtin_amdgcn_mfma_f32_16x16x32_bf16(a0, bf[j], ro[j], 0, 0, 0);
        }
    }

    const float* asrc = atomf + (size_t)b * Aa * AFD;
#pragma unroll
    for (int c = 0; c < 3; ++c) {          // atomf region, K cols [0,192)
#pragma unroll
        for (int ks = 0; ks < 2; ++ks) {
            const int c0 = c * 64 + ks * 32 + quad * 8;
            const int row = wave * 16 + l15;
            bf16x8 a0 = ld_frag_f32(asrc + (size_t)row * AFD + c0, c0, AFD);
            bf16x8 bf[8];
#pragma unroll
            for (int j = 0; j < 8; ++j)
                bf[j] = *(const bf16x8*)&Wo_b[(j * 16 + l15) * KWO + c0];
#pragma unroll
            for (int j = 0; j < 8; ++j)
                ro[j] = __builtin_amdgcn_mfma_f32_16x16x32_bf16(a0, bf[j], ro[j], 0, 0, 0);
        }
    }

    const int base = pfx[b];
#pragma unroll
    for (int j = 0; j < 8; ++j) {
        int col = j * 16 + l15;
        float bv = bo[col];
#pragma unroll
        for (int reg = 0; reg < 4; ++reg) {
            int a = wave * 16 + quad * 4 + reg;
            if (a < len) {
                float v = ro[j][reg] + bv;
                out[(size_t)(base + a) * Hh + col] = v > 0.f ? v : 0.f;
            }
        }
    }
}

// ---------------------------------------------------------------------------
extern "C" void kernel_launch(void* const* d_in, const int* in_sizes, int n_in,
                              void* d_out, int out_size, void* d_ws, size_t ws_size,
                              hipStream_t stream) {
    const float* atom_feature = (const float*)d_in[0];
    const float* f_ini        = (const float*)d_in[1];
    const int*   a2ib         = (const int*)d_in[2];
    const int*   mapping      = (const int*)d_in[3];
    const int*   mol_lens     = (const int*)d_in[5];
    const float* Wi           = (const float*)d_in[6];
    const float* Wh           = (const float*)d_in[7];
    const float* Wo           = (const float*)d_in[8];
    const float* bo           = (const float*)d_in[9];
    float* out = (float*)d_out;

    ushort* Wi_b = (ushort*)d_ws;
    ushort* Wh_b = Wi_b + 128 * KWI;
    ushort* Wo_b = Wh_b + 128 * Hh;
    int*    pfx  = (int*)(Wo_b + 128 * KWO);

    float* cmask = out + ((size_t)out_size - (size_t)Bm * Aa);

    k_prep_w<<<128, 256, 0, stream>>>(Wi, Wh, Wo, Wi_b, Wh_b, Wo_b);
    k_scan  <<<1, 512, 0, stream>>>(mol_lens, pfx);
    k_fused <<<Bm, 512, 0, stream>>>(atom_feature, f_ini, a2ib, mapping,
                                     Wi_b, Wh_b, Wo_b, bo, mol_lens, pfx,
                                     out, cmask);
}

// Round 3
// 274.569 us; speedup vs baseline: 1.3899x; 1.3899x over previous
//
#include <hip/hip_runtime.h>
#include <hip/hip_bf16.h>

typedef unsigned int   uint;
typedef unsigned short ushort;
typedef short bf16x8 __attribute__((ext_vector_type(8)));
typedef float f32x4  __attribute__((ext_vector_type(4)));

// Problem constants
constexpr int Bm   = 512;   // molecules
constexpr int Aa   = 128;   // atoms / molecule
constexpr int Ee   = 256;   // directed bonds / molecule
constexpr int Kk   = 6;     // incoming gathered
constexpr int AFD  = 133;
constexpr int FD   = 147;   // 133+14
constexpr int Hh   = 128;
constexpr int CATD = 261;   // 133+128
constexpr int KWI  = 192;   // Wi_b row stride (147 real + 45 zero)
constexpr int KWO  = 320;   // Wo_b row stride: [0,133) atomf cols, [133,192) zero, [192,320) m2a cols
constexpr int MST  = 136;   // msg LDS row stride (bf16)

// ---- bf16 helpers ----------------------------------------------------------
__device__ __forceinline__ ushort f2b(float f) {
    uint u = __float_as_uint(f);
    u += 0x7FFFu + ((u >> 16) & 1u);
    return (ushort)(u >> 16);
}
__device__ __forceinline__ uint cvt2(float x, float y) {   // v_cvt_pk_bf16_f32
    float2 t2; t2.x = x; t2.y = y;
    __hip_bfloat162 t = __float22bfloat162_rn(t2);
    uint r; __builtin_memcpy(&r, &t, 4); return r;
}
__device__ __forceinline__ float2 b2f2(uint p) {
    float2 r;
    r.x = __uint_as_float(p << 16);
    r.y = __uint_as_float(p & 0xFFFF0000u);
    return r;
}

// sum 6 bf16 rows (16B slices) from LDS msg, repack to an MFMA A-frag
__device__ __forceinline__ bf16x8 gsum6(const ushort* src, const int* mr, int ko) {
    float2 s0 = {0.f, 0.f}, s1 = {0.f, 0.f}, s2 = {0.f, 0.f}, s3 = {0.f, 0.f};
#pragma unroll
    for (int k = 0; k < Kk; ++k) {
        uint4 m = *(const uint4*)&src[mr[k] + ko];
        float2 a = b2f2(m.x); s0.x += a.x; s0.y += a.y;
        float2 b = b2f2(m.y); s1.x += b.x; s1.y += b.y;
        float2 d = b2f2(m.z); s2.x += d.x; s2.y += d.y;
        float2 e = b2f2(m.w); s3.x += e.x; s3.y += e.y;
    }
    uint4 o;
    o.x = cvt2(s0.x, s0.y); o.y = cvt2(s1.x, s1.y);
    o.z = cvt2(s2.x, s2.y); o.w = cvt2(s3.x, s3.y);
    bf16x8 r;
    __builtin_memcpy(&r, &o, 16);
    return r;
}

// build A-frag straight from global fp32 (8 predicated dword loads + 4 cvt_pk)
__device__ __forceinline__ bf16x8 ld_frag_f32(const float* sp, int c0, int lim) {
    float v[8];
#pragma unroll
    for (int d = 0; d < 8; ++d) v[d] = (c0 + d < lim) ? sp[d] : 0.f;
    uint4 o;
    o.x = cvt2(v[0], v[1]); o.y = cvt2(v[2], v[3]);
    o.z = cvt2(v[4], v[5]); o.w = cvt2(v[6], v[7]);
    bf16x8 r;
    __builtin_memcpy(&r, &o, 16);
    return r;
}

// ---------------------------------------------------------------------------
// Weight prep: fp32 -> padded bf16 (tiny; runs once)
// ---------------------------------------------------------------------------
__global__ __launch_bounds__(256) void k_prep_w(const float* __restrict__ Wi,
                                                const float* __restrict__ Wh,
                                                const float* __restrict__ Wo,
                                                ushort* __restrict__ Wi_b,
                                                ushort* __restrict__ Wh_b,
                                                ushort* __restrict__ Wo_b) {
    const int h = blockIdx.x, t = threadIdx.x;
    for (int c = t; c < KWI; c += 256)
        Wi_b[h * KWI + c] = f2b(c < FD ? Wi[h * FD + c] : 0.f);
    for (int c = t; c < Hh; c += 256)
        Wh_b[h * Hh + c] = f2b(Wh[h * Hh + c]);
    for (int c = t; c < KWO; c += 256) {
        float v = 0.f;
        if (c < AFD)       v = Wo[h * CATD + c];
        else if (c >= 192) v = Wo[h * CATD + AFD + (c - 192)];
        Wo_b[h * KWO + c] = f2b(v);
    }
}

__global__ __launch_bounds__(512) void k_scan(const int* __restrict__ ml,
                                              int* __restrict__ pfx) {
    __shared__ int s[512];
    int t = threadIdx.x;
    s[t] = ml[t];
    __syncthreads();
    for (int off = 1; off < 512; off <<= 1) {
        int v = (t >= off) ? s[t - off] : 0;
        __syncthreads();
        s[t] += v;
        __syncthreads();
    }
    pfx[t + 1] = s[t];
    if (t == 0) pfx[0] = 0;
}

// ---------------------------------------------------------------------------
// Fused DMPNN, single-LDS-buffer. One block = one molecule.
// LDS = msg(69.6K) + maps(9.2K) = 78,848 B  ->  2 blocks/CU fit (157.7 KB).
// __launch_bounds__(512,2): empirically the spill-free 128-VGPR cap on this
// compiler (512-thread blocks; (512,4) capped at 64 and spilled 600 MB).
// VGPR=128 => 4 waves/SIMD => both blocks fully resident.
//   Phase 1: inp = fini @ Wi^T   (A-frags direct from global fp32, no
//            staging, no barriers). inp kept packed-bf16 in 16 VGPRs/lane.
//            msg = relu(inp).
//   Phase 2: 2 hops, IN PLACE: acc init = inp; gather6(msg)@Wh^T (reads only)
//            -> barrier -> msg = relu(acc) -> barrier.
//   Phase 3: readout: m2a gather (LDS) + atomf (direct global), masked store.
// j-loops split in halves of 4 to keep peak live B-fragments at 16 VGPRs.
// ---------------------------------------------------------------------------
__global__ __launch_bounds__(512, 2) void k_fused(
        const float* __restrict__ atomf,
        const float* __restrict__ fini,
        const int*   __restrict__ a2ib,
        const int*   __restrict__ mapping,
        const ushort* __restrict__ Wi_b,
        const ushort* __restrict__ Wh_b,
        const ushort* __restrict__ Wo_b,
        const float* __restrict__ bo,
        const int*   __restrict__ mol_lens,
        const int*   __restrict__ pfx,
        float* __restrict__ out,
        float* __restrict__ cmask) {
    __shared__ ushort msg[Ee * MST];       // 69,632 B
    __shared__ int    map_s[Ee * Kk];      //  6,144 B
    __shared__ int    a2_s[Aa * Kk];       //  3,072 B   -> 78,848 B total

    const int b    = blockIdx.x;
    const int tid  = threadIdx.x;
    const int wave = tid >> 6;
    const int lane = tid & 63;
    const int l15  = lane & 15, quad = lane >> 4;

    for (int i = tid; i < Ee * Kk; i += 512) map_s[i] = mapping[b * Ee * Kk + i];
    for (int i = tid; i < Aa * Kk; i += 512) a2_s[i]  = a2ib[b * Aa * Kk + i];
    const int len = mol_lens[b];
    if (tid < Aa) cmask[b * Aa + tid] = (tid < len) ? 1.0f : 0.0f;

    // ---- Phase 1: inp = fini @ Wi^T  (barrier-free) ---------------------
    f32x4 acc[2][8];
#pragma unroll
    for (int i = 0; i < 2; ++i)
#pragma unroll
        for (int j = 0; j < 8; ++j) acc[i][j] = (f32x4){0.f, 0.f, 0.f, 0.f};

    const float* fsrc = fini + (size_t)b * Ee * FD;
#pragma unroll
    for (int c = 0; c < 3; ++c) {
#pragma unroll
        for (int ks = 0; ks < 2; ++ks) {
            const int c0 = c * 64 + ks * 32 + quad * 8;   // global K col base
            bf16x8 af[2];
#pragma unroll
            for (int i = 0; i < 2; ++i) {
                const int row = wave * 32 + i * 16 + l15;
                af[i] = ld_frag_f32(fsrc + (size_t)row * FD + c0, c0, FD);
            }
#pragma unroll
            for (int jh = 0; jh < 2; ++jh) {
                bf16x8 bf[4];
#pragma unroll
                for (int j = 0; j < 4; ++j)
                    bf[j] = *(const bf16x8*)&Wi_b[((jh * 4 + j) * 16 + l15) * KWI + c0];
#pragma unroll
                for (int i = 0; i < 2; ++i)
#pragma unroll
                    for (int j = 0; j < 4; ++j)
                        acc[i][jh * 4 + j] = __builtin_amdgcn_mfma_f32_16x16x32_bf16(
                            af[i], bf[j], acc[i][jh * 4 + j], 0, 0, 0);
            }
        }
    }

    // inp -> packed bf16 regs; msg = relu(inp)
    uint2 inp_pk[2][8];
#pragma unroll
    for (int i = 0; i < 2; ++i)
#pragma unroll
        for (int j = 0; j < 8; ++j) {
            f32x4 a4 = acc[i][j];
            uint2 p;
            p.x = cvt2(a4[0], a4[1]);
            p.y = cvt2(a4[2], a4[3]);
            inp_pk[i][j] = p;
            int col = j * 16 + l15;
#pragma unroll
            for (int reg = 0; reg < 4; ++reg) {
                int row = wave * 32 + i * 16 + quad * 4 + reg;
                float v = a4[reg] > 0.f ? a4[reg] : 0.f;
                msg[row * MST + col] = f2b(v);
            }
        }
    __syncthreads();   // msg + map_s/a2_s visible

    // gather row offsets (same for both hops)
    int mr[2][Kk];
#pragma unroll
    for (int i = 0; i < 2; ++i) {
        int row = wave * 32 + i * 16 + l15;
#pragma unroll
        for (int k = 0; k < Kk; ++k) mr[i][k] = map_s[row * Kk + k] * MST;
    }

    // ---- Phase 2: two in-place hops -------------------------------------
#pragma unroll
    for (int h = 0; h < 2; ++h) {
        // acc starts at inp (pre-activation, bf16-rounded)
#pragma unroll
        for (int i = 0; i < 2; ++i)
#pragma unroll
            for (int j = 0; j < 8; ++j) {
                float2 lo = b2f2(inp_pk[i][j].x);
                float2 hi = b2f2(inp_pk[i][j].y);
                acc[i][j] = (f32x4){lo.x, lo.y, hi.x, hi.y};
            }
#pragma unroll
        for (int ks = 0; ks < 4; ++ks) {
            const int ko = ks * 32 + quad * 8;
            bf16x8 af[2];
#pragma unroll
            for (int i = 0; i < 2; ++i) af[i] = gsum6(msg, mr[i], ko);
#pragma unroll
            for (int jh = 0; jh < 2; ++jh) {
                bf16x8 bf[4];
#pragma unroll
                for (int j = 0; j < 4; ++j)
                    bf[j] = *(const bf16x8*)&Wh_b[((jh * 4 + j) * 16 + l15) * Hh + ko];
#pragma unroll
                for (int i = 0; i < 2; ++i)
#pragma unroll
                    for (int j = 0; j < 4; ++j)
                        acc[i][jh * 4 + j] = __builtin_amdgcn_mfma_f32_16x16x32_bf16(
                            af[i], bf[j], acc[i][jh * 4 + j], 0, 0, 0);
            }
        }
        __syncthreads();   // all gathers done; safe to overwrite msg
#pragma unroll
        for (int i = 0; i < 2; ++i)
#pragma unroll
            for (int j = 0; j < 8; ++j) {
                int col = j * 16 + l15;
#pragma unroll
                for (int reg = 0; reg < 4; ++reg) {
                    int row = wave * 32 + i * 16 + quad * 4 + reg;
                    float v = acc[i][j][reg];
                    msg[row * MST + col] = f2b(v > 0.f ? v : 0.f);
                }
            }
        __syncthreads();   // new msg visible
    }

    // ---- Phase 3: readout (barrier-free) --------------------------------
    f32x4 ro[8];
#pragma unroll
    for (int j = 0; j < 8; ++j) ro[j] = (f32x4){0.f, 0.f, 0.f, 0.f};

    {   // m2a gather region, K cols [192,320) of Wo
        int ar[Kk];
        const int row = wave * 16 + l15;
#pragma unroll
        for (int k = 0; k < Kk; ++k) ar[k] = a2_s[row * Kk + k] * MST;
#pragma unroll
        for (int ks = 0; ks < 4; ++ks) {
            const int ko = ks * 32 + quad * 8;
            bf16x8 a0 = gsum6(msg, ar, ko);
#pragma unroll
            for (int jh = 0; jh < 2; ++jh) {
                bf16x8 bf[4];
#pragma unroll
                for (int j = 0; j < 4; ++j)
                    bf[j] = *(const bf16x8*)&Wo_b[((jh * 4 + j) * 16 + l15) * KWO + 192 + ko];
#pragma unroll
                for (int j = 0; j < 4; ++j)
                    ro[jh * 4 + j] = __builtin_amdgcn_mfma_f32_16x16x32_bf16(
                        a0, bf[j], ro[jh * 4 + j], 0, 0, 0);
            }
        }
    }

    const float* asrc = atomf + (size_t)b * Aa * AFD;
#pragma unroll
    for (int c = 0; c < 3; ++c) {          // atomf region, K cols [0,192)
#pragma unroll
        for (int ks = 0; ks < 2; ++ks) {
            const int c0 = c * 64 + ks * 32 + quad * 8;
            const int row = wave * 16 + l15;
            bf16x8 a0 = ld_frag_f32(asrc + (size_t)row * AFD + c0, c0, AFD);
#pragma unroll
            for (int jh = 0; jh < 2; ++jh) {
                bf16x8 bf[4];
#pragma unroll
                for (int j = 0; j < 4; ++j)
                    bf[j] = *(const bf16x8*)&Wo_b[((jh * 4 + j) * 16 + l15) * KWO + c0];
#pragma unroll
                for (int j = 0; j < 4; ++j)
                    ro[jh * 4 + j] = __builtin_amdgcn_mfma_f32_16x16x32_bf16(
                        a0, bf[j], ro[jh * 4 + j], 0, 0, 0);
            }
        }
    }

    const int base = pfx[b];
#pragma unroll
    for (int j = 0; j < 8; ++j) {
        int col = j * 16 + l15;
        float bv = bo[col];
#pragma unroll
        for (int reg = 0; reg < 4; ++reg) {
            int a = wave * 16 + quad * 4 + reg;
            if (a < len) {
                float v = ro[j][reg] + bv;
                out[(size_t)(base + a) * Hh + col] = v > 0.f ? v : 0.f;
            }
        }
    }
}

// ---------------------------------------------------------------------------
extern "C" void kernel_launch(void* const* d_in, const int* in_sizes, int n_in,
                              void* d_out, int out_size, void* d_ws, size_t ws_size,
                              hipStream_t stream) {
    const float* atom_feature = (const float*)d_in[0];
    const float* f_ini        = (const float*)d_in[1];
    const int*   a2ib         = (const int*)d_in[2];
    const int*   mapping      = (const int*)d_in[3];
    const int*   mol_lens     = (const int*)d_in[5];
    const float* Wi           = (const float*)d_in[6];
    const float* Wh           = (const float*)d_in[7];
    const float* Wo           = (const float*)d_in[8];
    const float* bo           = (const float*)d_in[9];
    float* out = (float*)d_out;

    ushort* Wi_b = (ushort*)d_ws;
    ushort* Wh_b = Wi_b + 128 * KWI;
    ushort* Wo_b = Wh_b + 128 * Hh;
    int*    pfx  = (int*)(Wo_b + 128 * KWO);

    float* cmask = out + ((size_t)out_size - (size_t)Bm * Aa);

    k_prep_w<<<128, 256, 0, stream>>>(Wi, Wh, Wo, Wi_b, Wh_b, Wo_b);
    k_scan  <<<1, 512, 0, stream>>>(mol_lens, pfx);
    k_fused <<<Bm, 512, 0, stream>>>(atom_feature, f_ini, a2ib, mapping,
                                     Wi_b, Wh_b, Wo_b, bo, mol_lens, pfx,
                                     out, cmask);
}